// Round 4
// baseline (187.434 us; speedup 1.0000x reference)
//
#include <hip/hip_runtime.h>

// Problem constants (fp32 RQ-VAE nearest-codebook step)
#define Bn 8192
#define Kn 8192
#define Dn 512
#define WINDOW 0.25f   // refine window: covers f16-noise + 8-bit mantissa packing

typedef _Float16 half8 __attribute__((ext_vector_type(8)));
typedef float floatx4 __attribute__((ext_vector_type(4)));
typedef unsigned long long u64;

// Order-preserving map float -> u32 (monotone under unsigned compare, finite inputs)
__device__ __forceinline__ unsigned int fkey(float f) {
    unsigned int u = __float_as_uint(f);
    return (u & 0x80000000u) ? ~u : (u | 0x80000000u);
}

// async global->LDS, 16B per lane (global_load_lds_dwordx4)
__device__ __forceinline__ void gld16(const _Float16* g, _Float16* l) {
    __builtin_amdgcn_global_load_lds(
        (const __attribute__((address_space(1))) unsigned int*)g,
        (__attribute__((address_space(3))) unsigned int*)l, 16, 0, 0);
}

// ---------------- kernel: e_sq (fallback path only) ----------------
__global__ __launch_bounds__(256) void esq_kernel(const float* __restrict__ E,
                                                  float* __restrict__ esq) {
    int wave = threadIdx.x >> 6;
    int lane = threadIdx.x & 63;
    int k = blockIdx.x * 4 + wave;
    const float4* row = (const float4*)(E + (size_t)k * Dn);
    float4 v0 = row[lane];
    float4 v1 = row[64 + lane];
    float s = v0.x*v0.x + v0.y*v0.y + v0.z*v0.z + v0.w*v0.w
            + v1.x*v1.x + v1.y*v1.y + v1.z*v1.z + v1.w*v1.w;
    #pragma unroll
    for (int off = 32; off > 0; off >>= 1) s += __shfl_down(s, off, 64);
    if (lane == 0) esq[k] = s;
}

// ---------------- kernel: fp32 -> f16 (hi), PACKED layout, + fused e_sq ------
// G[panel][chunk][slot]*8 halves, panel = 128 rows, chunk = 32 k-halves,
//   slot(row128, kq) = (row128>>6)*256 + ((row128>>4)&3)*64 + kq*16 + (row128&15)
// blocks [0,1024) pack X, [1024,2048) pack E (E blocks also atomicAdd e_sq
// partials; esq must be zeroed before launch).
__global__ __launch_bounds__(256) void convert_hi(
    const float* __restrict__ X, const float* __restrict__ E,
    _Float16* __restrict__ Xh, _Float16* __restrict__ Eh,
    float* __restrict__ esq)
{
    const bool isE = blockIdx.x >= 1024;
    const int pc = blockIdx.x & 1023;
    const int panel = pc >> 4;              // 64 panels of 128 rows
    const int chunk = pc & 15;              // 16 chunks of 32 halves
    const float* src = isE ? E : X;
    _Float16* dst = isE ? Eh : Xh;
    const int t = threadIdx.x;
    const int row = t >> 1;                 // [0,128)
    const int kh  = (t & 1) * 16;
    const float* p = &src[(size_t)(panel * 128 + row) * Dn + chunk * 32 + kh];
    float4 v[4];
    v[0] = *(const float4*)(p + 0);
    v[1] = *(const float4*)(p + 4);
    v[2] = *(const float4*)(p + 8);
    v[3] = *(const float4*)(p + 12);
    const int slotbase = ((row >> 6) << 8) + (((row >> 4) & 3) << 6) + (row & 15);
    #pragma unroll
    for (int j = 0; j < 2; ++j) {
        half8 h;
        #pragma unroll
        for (int q = 0; q < 2; ++q) {
            const float4 w = v[j * 2 + q];
            h[q*4+0]=(_Float16)w.x; h[q*4+1]=(_Float16)w.y;
            h[q*4+2]=(_Float16)w.z; h[q*4+3]=(_Float16)w.w;
        }
        const int kq = (t & 1) * 2 + j;
        const size_t off = ((size_t)(panel * 16 + chunk) * 512
                            + slotbase + kq * 16) * 8;
        *(half8*)&dst[off] = h;
    }
    if (isE) {
        float s = 0.f;
        #pragma unroll
        for (int i = 0; i < 4; ++i)
            s += v[i].x*v[i].x + v[i].y*v[i].y + v[i].z*v[i].z + v[i].w*v[i].w;
        s += __shfl_xor(s, 1);              // pair (kh=0, kh=16) -> 32-col partial
        if ((t & 1) == 0) atomicAdd(&esq[panel * 128 + row], s);
    }
}

// ---------------- kernel: hi-only MFMA, 256x256, m201 8-phase discipline -----
// d~(b,k) = e_sq[k] - 2*(xh.eh). Block = 256 rows x 256 cols, 512 threads =
// 8 waves (wm 2 x wn 4), wave tile 128x64 -> acc 8x4 of 16x16 frags.
// K-loop: 8 K-tiles of BK=64 (2 packed chunks kh0/kh1), LDS 128KB = 2 K-tile
// buffers. SCHEDULE = verified m201 template (learn_hip, 62% MfmaUtil at the
// SAME occupancy): per 16-MFMA phase:
//   { ds_read cluster ; issue 1 stage group ; s_barrier ;
//     s_waitcnt lgkmcnt(0) ; sched_barrier(0)   [rule #18] ;
//     setprio(1) ; 16 MFMA ; setprio(0) ; [vmcnt(4) at P1/P3] ; s_barrier }
// The double barrier per phase forces cross-wave read/MFMA alternation (the
// convoy after a single barrier left both pipes ~28% busy, r3 counters);
// read latency is absorbed in the leading-barrier skew window. vmcnt is
// COUNTED (4) at the two publication points per K-tile - never 0 in the main
// loop (m218: counted-vs-drain0 = +38-73%). Packed slot layout ->
// conflict-free ds_read_b128 (r3: SQ_LDS_BANK_CONFLICT ~ 0).
__global__ __launch_bounds__(512, 2) void argmin_hi(
    const _Float16* __restrict__ Xh, const _Float16* __restrict__ Eh,
    const float* __restrict__ esq, float* __restrict__ bestf)
{
    __shared__ __align__(16) _Float16 sA[2][2][2][4096];   // [buf][kh][panel][4096] 64KB
    __shared__ __align__(16) _Float16 sB[2][2][2][4096];   // 64KB

    const int tid  = threadIdx.x;
    const int bid  = blockIdx.x;
    const int bx   = bid & 31;           // E col-block: bx%8 fixed per XCD -> ~1MB L2 set
    const int by   = bid >> 5;           // X row-block
    const int lane = tid & 63, wave = tid >> 6;
    const int wm   = wave >> 2;          // 0..1: 128-row half
    const int wn   = wave & 3;           // 0..3: 64-col quarter
    const int colg = lane & 15, quad = lane >> 4;

    const _Float16* gA = Xh + (size_t)(2 * by) * 65536 + tid * 8;
    const _Float16* gB = Eh + (size_t)(2 * bx) * 65536 + tid * 8;

    auto stgA = [&](int t, int kh, int b) {
        const int c = (2 * t + kh) * 4096;
        gld16(gA + c,         &sA[b][kh][0][tid * 8]);
        gld16(gA + 65536 + c, &sA[b][kh][1][tid * 8]);
    };
    auto stgB = [&](int t, int kh, int b) {
        const int c = (2 * t + kh) * 4096;
        gld16(gB + c,         &sB[b][kh][0][tid * 8]);
        gld16(gB + 65536 + c, &sB[b][kh][1][tid * 8]);
    };

    floatx4 acc[8][4];
    #pragma unroll
    for (int i = 0; i < 8; ++i)
        #pragma unroll
        for (int j = 0; j < 4; ++j) acc[i][j] = {0.f, 0.f, 0.f, 0.f};

    // prologue: K-tile 0 -> buf 0 (4 groups, 8 loads); publish kh0(0)
    stgA(0, 0, 0); stgB(0, 0, 0); stgA(0, 1, 0); stgB(0, 1, 0);
    asm volatile("s_waitcnt vmcnt(4)" ::: "memory");
    __builtin_amdgcn_s_barrier();

    const int la8 = lane * 8;
    const int bo  = (wn & 1) * 2048 + la8;

    for (int t = 0; t < 8; ++t) {
        const int b = t & 1, nb = b ^ 1;
        const bool pf = (t < 7);
        const _Float16* A0 = &sA[b][0][wm][0];
        const _Float16* A1 = &sA[b][1][wm][0];
        const _Float16* B0 = &sB[b][0][wn >> 1][bo];
        const _Float16* B1 = &sB[b][1][wn >> 1][bo];
        half8 a[4], bb[4];

        // ---- P0: kh0, rows 0-63; stage A(t+1,kh0)
        #pragma unroll
        for (int ni = 0; ni < 4; ++ni) bb[ni] = *(const half8*)&B0[ni * 512];
        #pragma unroll
        for (int i = 0; i < 4; ++i)   a[i]  = *(const half8*)&A0[i * 512 + la8];
        if (pf) stgA(t + 1, 0, nb);
        __builtin_amdgcn_s_barrier();
        asm volatile("s_waitcnt lgkmcnt(0)" ::: "memory");
        __builtin_amdgcn_sched_barrier(0);
        __builtin_amdgcn_s_setprio(1);
        #pragma unroll
        for (int i = 0; i < 4; ++i)
            #pragma unroll
            for (int ni = 0; ni < 4; ++ni)
                acc[i][ni] = __builtin_amdgcn_mfma_f32_16x16x32_f16(
                    a[i], bb[ni], acc[i][ni], 0, 0, 0);
        __builtin_amdgcn_s_setprio(0);
        __builtin_amdgcn_s_barrier();

        // ---- P1: kh0, rows 64-127 (bb reused); stage B(t+1,kh0); publish kh1(t)
        #pragma unroll
        for (int i = 0; i < 4; ++i) a[i] = *(const half8*)&A0[2048 + i * 512 + la8];
        if (pf) stgB(t + 1, 0, nb);
        __builtin_amdgcn_s_barrier();
        asm volatile("s_waitcnt lgkmcnt(0)" ::: "memory");
        __builtin_amdgcn_sched_barrier(0);
        __builtin_amdgcn_s_setprio(1);
        #pragma unroll
        for (int i = 0; i < 4; ++i)
            #pragma unroll
            for (int ni = 0; ni < 4; ++ni)
                acc[4 + i][ni] = __builtin_amdgcn_mfma_f32_16x16x32_f16(
                    a[i], bb[ni], acc[4 + i][ni], 0, 0, 0);
        __builtin_amdgcn_s_setprio(0);
        if (pf) asm volatile("s_waitcnt vmcnt(4)" ::: "memory");
        else    asm volatile("s_waitcnt vmcnt(0)" ::: "memory");
        __builtin_amdgcn_s_barrier();

        // ---- P2: kh1, rows 0-63; stage A(t+1,kh1)
        #pragma unroll
        for (int ni = 0; ni < 4; ++ni) bb[ni] = *(const half8*)&B1[ni * 512];
        #pragma unroll
        for (int i = 0; i < 4; ++i)   a[i]  = *(const half8*)&A1[i * 512 + la8];
        if (pf) stgA(t + 1, 1, nb);
        __builtin_amdgcn_s_barrier();
        asm volatile("s_waitcnt lgkmcnt(0)" ::: "memory");
        __builtin_amdgcn_sched_barrier(0);
        __builtin_amdgcn_s_setprio(1);
        #pragma unroll
        for (int i = 0; i < 4; ++i)
            #pragma unroll
            for (int ni = 0; ni < 4; ++ni)
                acc[i][ni] = __builtin_amdgcn_mfma_f32_16x16x32_f16(
                    a[i], bb[ni], acc[i][ni], 0, 0, 0);
        __builtin_amdgcn_s_setprio(0);
        __builtin_amdgcn_s_barrier();

        // ---- P3: kh1, rows 64-127; stage B(t+1,kh1); publish kh0(t+1)
        #pragma unroll
        for (int i = 0; i < 4; ++i) a[i] = *(const half8*)&A1[2048 + i * 512 + la8];
        if (pf) stgB(t + 1, 1, nb);
        __builtin_amdgcn_s_barrier();
        asm volatile("s_waitcnt lgkmcnt(0)" ::: "memory");
        __builtin_amdgcn_sched_barrier(0);
        __builtin_amdgcn_s_setprio(1);
        #pragma unroll
        for (int i = 0; i < 4; ++i)
            #pragma unroll
            for (int ni = 0; ni < 4; ++ni)
                acc[4 + i][ni] = __builtin_amdgcn_mfma_f32_16x16x32_f16(
                    a[i], bb[ni], acc[4 + i][ni], 0, 0, 0);
        __builtin_amdgcn_s_setprio(0);
        if (pf) asm volatile("s_waitcnt vmcnt(4)" ::: "memory");
        else    asm volatile("s_waitcnt vmcnt(0)" ::: "memory");
        __builtin_amdgcn_s_barrier();
    }

    // ---- epilogue: per-(mi,r) top-2 over the wave's 64 cols, then cross-wn
    // merge in LDS -> top-2 per 256-col block (same granularity as before).
    float2* sm = (float2*)&sA[0][0][0][0];   // 8KB merge buffer
    const int n0 = bx * 256 + wn * 64;
    float eqv[4];
    #pragma unroll
    for (int ni = 0; ni < 4; ++ni) eqv[ni] = esq[n0 + ni * 16 + colg];
    const unsigned ob_base = ((unsigned)colg << 4) | ((unsigned)wn << 2);

    #pragma unroll
    for (int mi = 0; mi < 8; ++mi)
        #pragma unroll
        for (int r = 0; r < 4; ++r) {
            float w1 = INFINITY, w2 = INFINITY;
            #pragma unroll
            for (int ni = 0; ni < 4; ++ni) {
                const float dv = eqv[ni] - 2.0f * acc[mi][ni][r];
                const float key = __uint_as_float(
                    (__float_as_uint(dv) & 0xFFFFFF00u) | (ob_base | (unsigned)ni));
                w2 = fminf(w2, fmaxf(w1, key));
                w1 = fminf(w1, key);
            }
            #pragma unroll
            for (int off = 1; off < 16; off <<= 1) {
                const float p1 = __shfl_xor(w1, off);
                const float p2 = __shfl_xor(w2, off);
                w2 = fminf(fmaxf(w1, p1), fminf(w2, p2));
                w1 = fminf(w1, p1);
            }
            if (colg == 0) {
                const int row128 = mi * 16 + quad * 4 + r;
                float2 st; st.x = w1; st.y = w2;
                sm[(wm * 128 + row128) * 4 + wn] = st;
            }
        }
    __syncthreads();
    if (tid < 256) {
        float m1 = INFINITY, m2 = INFINITY;
        #pragma unroll
        for (int w = 0; w < 4; ++w) {
            const float2 p = sm[tid * 4 + w];
            m2 = fminf(fmaxf(m1, p.x), fminf(m2, p.y));
            m1 = fminf(m1, p.x);
        }
        float2 st; st.x = m1; st.y = m2;
        *(float2*)&bestf[(size_t)(by * 256 + tid) * 64 + bx * 2] = st;
    }
}

// ---------------- kernel: exact refine, ONE WAVE PER ROW ---------------------
// 64 lanes read the row's 64 stored keys (top-2 per 256-col block), wave-min
// -> threshold -> ballot survivors -> exact fp32 distance per survivor ->
// best index (u64 key: ties to lowest index) -> write index + residual.
__global__ __launch_bounds__(256) void refine_kernel(
    const float* __restrict__ X, const float* __restrict__ E,
    const float* __restrict__ bestf, float* __restrict__ out)
{
    const int lane = threadIdx.x & 63, wave = threadIdx.x >> 6;
    const int b = blockIdx.x * 4 + wave;

    const float val = bestf[(size_t)b * 64 + lane];
    // decode this slot's candidate column: slot = cb*2 + j, cb = 256-col block
    const unsigned bits = __float_as_uint(val);
    const int cb = lane >> 1;
    const int colg = (bits >> 4) & 15, wn = (bits >> 2) & 3, ni = bits & 3;
    const int col = cb * 256 + wn * 64 + ni * 16 + colg;

    float mn = val;
    #pragma unroll
    for (int off = 1; off < 64; off <<= 1) mn = fminf(mn, __shfl_xor(mn, off));

    const float4* xr = (const float4*)(X + (size_t)b * Dn);
    const float4 x0 = xr[lane * 2], x1 = xr[lane * 2 + 1];

    u64 bestk = ~0ull;
    u64 mask = __ballot(val <= mn + WINDOW);
    while (mask) {
        const int s = __builtin_ctzll(mask);
        mask &= mask - 1;
        const int c = __shfl(col, s);
        const float4* er = (const float4*)(E + (size_t)c * Dn);
        const float4 e0 = er[lane * 2], e1 = er[lane * 2 + 1];
        float p = e0.x*(e0.x - 2.f*x0.x) + e0.y*(e0.y - 2.f*x0.y)
                + e0.z*(e0.z - 2.f*x0.z) + e0.w*(e0.w - 2.f*x0.w)
                + e1.x*(e1.x - 2.f*x1.x) + e1.y*(e1.y - 2.f*x1.y)
                + e1.z*(e1.z - 2.f*x1.z) + e1.w*(e1.w - 2.f*x1.w);
        #pragma unroll
        for (int off = 1; off < 64; off <<= 1) p += __shfl_xor(p, off);
        const u64 k = ((u64)fkey(p) << 32) | (u64)(unsigned int)c;
        if (k < bestk) bestk = k;
    }

    const int idx = (int)(unsigned int)(bestk & 0xFFFFFFFFull);
    if (lane == 0) out[b] = (float)idx;
    const float4* er = (const float4*)(E + (size_t)idx * Dn);
    const float4 e0 = er[lane * 2], e1 = er[lane * 2 + 1];
    float4 r0, r1;
    r0.x = x0.x - e0.x; r0.y = x0.y - e0.y; r0.z = x0.z - e0.z; r0.w = x0.w - e0.w;
    r1.x = x1.x - e1.x; r1.y = x1.y - e1.y; r1.z = x1.z - e1.z; r1.w = x1.w - e1.w;
    float4* o = (float4*)(out + Bn + (size_t)b * Dn);
    o[lane * 2] = r0; o[lane * 2 + 1] = r1;
}

// ---------------- fallback (round-1 fp32 path, used only if ws too small) ----
#define KSPLIT 16
#define LDSW 132
__global__ __launch_bounds__(256, 2) void argmin_fp32(
    const float* __restrict__ X, const float* __restrict__ E,
    const float* __restrict__ esq, u64* __restrict__ best)
{
    __shared__ __align__(16) float Xs[16][LDSW];
    __shared__ __align__(16) float Es[16][LDSW];
    __shared__ u64 red[128][16];
    const int tid = threadIdx.x;
    const int tx = tid & 15, ty = tid >> 4;
    const int rowTile = blockIdx.x / KSPLIT;
    const int split   = blockIdx.x % KSPLIT;
    const int m0 = rowTile * 128;
    const int kbase = split * (Kn / KSPLIT);
    float bestv[8]; int besti[8];
    #pragma unroll
    for (int i = 0; i < 8; ++i) { bestv[i] = INFINITY; besti[i] = 0; }
    const int ldRow = tid >> 2, ldD = (tid & 3) * 4;
    for (int kt = 0; kt < (Kn / KSPLIT) / 128; ++kt) {
        const int k0 = kbase + kt * 128;
        float acc[8][8] = {};
        for (int dc = 0; dc < Dn / 16; ++dc) {
            const int d0 = dc * 16;
            float4 xa = *(const float4*)&X[(size_t)(m0 + ldRow)      * Dn + d0 + ldD];
            float4 xb = *(const float4*)&X[(size_t)(m0 + 64 + ldRow) * Dn + d0 + ldD];
            float4 ea = *(const float4*)&E[(size_t)(k0 + ldRow)      * Dn + d0 + ldD];
            float4 eb = *(const float4*)&E[(size_t)(k0 + 64 + ldRow) * Dn + d0 + ldD];
            __syncthreads();
            Xs[ldD+0][ldRow] = xa.x; Xs[ldD+1][ldRow] = xa.y;
            Xs[ldD+2][ldRow] = xa.z; Xs[ldD+3][ldRow] = xa.w;
            Xs[ldD+0][64+ldRow] = xb.x; Xs[ldD+1][64+ldRow] = xb.y;
            Xs[ldD+2][64+ldRow] = xb.z; Xs[ldD+3][64+ldRow] = xb.w;
            Es[ldD+0][ldRow] = ea.x; Es[ldD+1][ldRow] = ea.y;
            Es[ldD+2][ldRow] = ea.z; Es[ldD+3][ldRow] = ea.w;
            Es[ldD+0][64+ldRow] = eb.x; Es[ldD+1][64+ldRow] = eb.y;
            Es[ldD+2][64+ldRow] = eb.z; Es[ldD+3][64+ldRow] = eb.w;
            __syncthreads();
            #pragma unroll
            for (int d = 0; d < 16; ++d) {
                float a8[8], b8[8];
                *(float4*)&a8[0] = *(const float4*)&Xs[d][4*ty];
                *(float4*)&a8[4] = *(const float4*)&Xs[d][64 + 4*ty];
                *(float4*)&b8[0] = *(const float4*)&Es[d][4*tx];
                *(float4*)&b8[4] = *(const float4*)&Es[d][64 + 4*tx];
                #pragma unroll
                for (int i = 0; i < 8; ++i)
                    #pragma unroll
                    for (int j = 0; j < 8; ++j) acc[i][j] += a8[i] * b8[j];
            }
        }
        #pragma unroll
        for (int j = 0; j < 8; ++j) {
            const int c = k0 + ((j < 4) ? (4*tx + j) : (64 + 4*tx + (j - 4)));
            const float eq = esq[c];
            #pragma unroll
            for (int i = 0; i < 8; ++i) {
                float dval = eq - 2.0f * acc[i][j];
                if (dval < bestv[i]) { bestv[i] = dval; besti[i] = c; }
            }
        }
    }
    #pragma unroll
    for (int i = 0; i < 8; ++i) {
        int rloc = (i < 4) ? (4*ty + i) : (64 + 4*ty + (i - 4));
        red[rloc][tx] = ((u64)fkey(bestv[i]) << 32) | (u64)(unsigned int)besti[i];
    }
    __syncthreads();
    if (tid < 128) {
        u64 m = red[tid][0];
        #pragma unroll
        for (int t = 1; t < 16; ++t) { u64 v = red[tid][t]; if (v < m) m = v; }
        best[(size_t)(m0 + tid) * KSPLIT + split] = m;
    }
}

__global__ __launch_bounds__(256) void finalize_kernel(
    const float* __restrict__ X, const float* __restrict__ E,
    const u64* __restrict__ best, float* __restrict__ out, int nsplits)
{
    __shared__ int sidx[2];
    const int half = threadIdx.x >> 7;
    const int t    = threadIdx.x & 127;
    const int b    = blockIdx.x * 2 + half;
    if (t < 64) {
        u64 v = (t < nsplits) ? best[(size_t)b * nsplits + t] : ~0ull;
        #pragma unroll
        for (int off = 1; off < 64; off <<= 1) {
            u64 o = __shfl_xor(v, off);
            if (o < v) v = o;
        }
        if (t == 0) {
            int idx = (int)(unsigned int)(v & 0xFFFFFFFFull);
            sidx[half] = idx;
            out[b] = (float)idx;
        }
    }
    __syncthreads();
    const int idx = sidx[half];
    float4 x = ((const float4*)(X + (size_t)b * Dn))[t];
    float4 e = ((const float4*)(E + (size_t)idx * Dn))[t];
    float4 r; r.x = x.x - e.x; r.y = x.y - e.y; r.z = x.z - e.z; r.w = x.w - e.w;
    ((float4*)(out + Bn + (size_t)b * Dn))[t] = r;
}

extern "C" void kernel_launch(void* const* d_in, const int* in_sizes, int n_in,
                              void* d_out, int out_size, void* d_ws, size_t ws_size,
                              hipStream_t stream) {
    const float* X = (const float*)d_in[0];   // previous_residual [B, D]
    const float* E = (const float*)d_in[1];   // codebook_embeddings [K, D]
    float* out = (float*)d_out;               // [B] idx-as-float ++ [B*D] residual

    // fast-path ws: esq 32KB | Xh 8MB | Eh 8MB | bestf 2MB  (~18.3 MB)
    const size_t HB = (size_t)Bn * Dn * sizeof(_Float16);        // 8 MB
    const size_t BESTB = (size_t)Bn * 64 * sizeof(float);        // 2 MB
    const size_t NEED = 32768 + 2 * HB + BESTB;

    float* esq = (float*)d_ws;

    if (ws_size >= NEED) {
        _Float16* Xh = (_Float16*)((char*)d_ws + 32768);
        _Float16* Eh = (_Float16*)((char*)d_ws + 32768 + HB);
        float* bestf = (float*)((char*)d_ws + 32768 + 2 * HB);
        hipMemsetAsync((void*)esq, 0, Kn * sizeof(float), stream);
        convert_hi<<<2048, 256, 0, stream>>>(X, E, Xh, Eh, esq);
        argmin_hi<<<1024, 512, 0, stream>>>(Xh, Eh, esq, bestf);
        refine_kernel<<<Bn / 4, 256, 0, stream>>>(X, E, bestf, out);
    } else {
        u64* best = (u64*)((char*)d_ws + 32768);
        esq_kernel<<<Kn / 4, 256, 0, stream>>>(E, esq);
        argmin_fp32<<<(Bn / 128) * KSPLIT, 256, 0, stream>>>(X, E, esq, best);
        finalize_kernel<<<Bn / 2, 256, 0, stream>>>(X, E, best, out, KSPLIT);
    }
}

// Round 6
// 178.557 us; speedup vs baseline: 1.0497x; 1.0497x over previous
//
#include <hip/hip_runtime.h>

// Problem constants (fp32 RQ-VAE nearest-codebook step)
#define Bn 8192
#define Kn 8192
#define Dn 512
#define WINDOW 0.25f   // refine window: covers f16-noise + 8-bit mantissa packing

typedef _Float16 half8 __attribute__((ext_vector_type(8)));
typedef float floatx4 __attribute__((ext_vector_type(4)));
typedef unsigned long long u64;

// Order-preserving map float -> u32 (monotone under unsigned compare, finite inputs)
__device__ __forceinline__ unsigned int fkey(float f) {
    unsigned int u = __float_as_uint(f);
    return (u & 0x80000000u) ? ~u : (u | 0x80000000u);
}

// async global->LDS, 16B per lane (global_load_lds_dwordx4)
__device__ __forceinline__ void gld16(const _Float16* g, _Float16* l) {
    __builtin_amdgcn_global_load_lds(
        (const __attribute__((address_space(1))) unsigned int*)g,
        (__attribute__((address_space(3))) unsigned int*)l, 16, 0, 0);
}

// ---------------- kernel: e_sq (fallback path only) ----------------
__global__ __launch_bounds__(256) void esq_kernel(const float* __restrict__ E,
                                                  float* __restrict__ esq) {
    int wave = threadIdx.x >> 6;
    int lane = threadIdx.x & 63;
    int k = blockIdx.x * 4 + wave;
    const float4* row = (const float4*)(E + (size_t)k * Dn);
    float4 v0 = row[lane];
    float4 v1 = row[64 + lane];
    float s = v0.x*v0.x + v0.y*v0.y + v0.z*v0.z + v0.w*v0.w
            + v1.x*v1.x + v1.y*v1.y + v1.z*v1.z + v1.w*v1.w;
    #pragma unroll
    for (int off = 32; off > 0; off >>= 1) s += __shfl_down(s, off, 64);
    if (lane == 0) esq[k] = s;
}

// ---------------- kernel: fp32 -> f16 (hi), PACKED layout, + fused e_sq ------
// G[panel][chunk][slot]*8 halves, panel = 128 rows, chunk = 32 k-halves,
//   slot(row128, kq) = (row128>>6)*256 + ((row128>>4)&3)*64 + kq*16 + (row128&15)
// blocks [0,1024) pack X, [1024,2048) pack E (E blocks also atomicAdd e_sq
// partials; esq must be zeroed before launch).
__global__ __launch_bounds__(256) void convert_hi(
    const float* __restrict__ X, const float* __restrict__ E,
    _Float16* __restrict__ Xh, _Float16* __restrict__ Eh,
    float* __restrict__ esq)
{
    const bool isE = blockIdx.x >= 1024;
    const int pc = blockIdx.x & 1023;
    const int panel = pc >> 4;              // 64 panels of 128 rows
    const int chunk = pc & 15;              // 16 chunks of 32 halves
    const float* src = isE ? E : X;
    _Float16* dst = isE ? Eh : Xh;
    const int t = threadIdx.x;
    const int row = t >> 1;                 // [0,128)
    const int kh  = (t & 1) * 16;
    const float* p = &src[(size_t)(panel * 128 + row) * Dn + chunk * 32 + kh];
    float4 v[4];
    v[0] = *(const float4*)(p + 0);
    v[1] = *(const float4*)(p + 4);
    v[2] = *(const float4*)(p + 8);
    v[3] = *(const float4*)(p + 12);
    const int slotbase = ((row >> 6) << 8) + (((row >> 4) & 3) << 6) + (row & 15);
    #pragma unroll
    for (int j = 0; j < 2; ++j) {
        half8 h;
        #pragma unroll
        for (int q = 0; q < 2; ++q) {
            const float4 w = v[j * 2 + q];
            h[q*4+0]=(_Float16)w.x; h[q*4+1]=(_Float16)w.y;
            h[q*4+2]=(_Float16)w.z; h[q*4+3]=(_Float16)w.w;
        }
        const int kq = (t & 1) * 2 + j;
        const size_t off = ((size_t)(panel * 16 + chunk) * 512
                            + slotbase + kq * 16) * 8;
        *(half8*)&dst[off] = h;
    }
    if (isE) {
        float s = 0.f;
        #pragma unroll
        for (int i = 0; i < 4; ++i)
            s += v[i].x*v[i].x + v[i].y*v[i].y + v[i].z*v[i].z + v[i].w*v[i].w;
        s += __shfl_xor(s, 1);              // pair (kh=0, kh=16) -> 32-col partial
        if ((t & 1) == 0) atomicAdd(&esq[panel * 128 + row], s);
    }
}

// ---------------- kernel: hi-only MFMA, 256x256, A-in-LDS / B-in-regs --------
// d~(b,k) = e_sq[k] - 2*(xh.eh). Block = 256 rows x 256 cols, 512 threads =
// 8 waves (wm 2 x wn 4), wave tile 128x64 -> acc 8x4 of 16x16 frags.
// DIAGNOSIS (r2/r3 counters): LDS read BW pinned at ~66 B/cyc/CU in BOTH
// prior schedules (m134 ds_read_b128 ceiling ~85) -> GEMM is LDS-read-bound,
// not sync-bound. FIX: B (Eh) is XCD-L2-resident by design (~1MB/XCD via
// bx%8), so load B DIRECT global->VGPR (ping-pong bbA/bbB, 1-kh lookahead,
// compiler-scheduled waits); only A stays in LDS. Per-wave LDS reads/tile
// 24KB->16KB, no B staging writes, LDS 64KB, and ONE counted
// vmcnt(4)+s_barrier per K-tile (stgA gld16 issued BEFORE the bb loads, so
// vmcnt(4) drains exactly the 4 gld16 and leaves the 4 bb loads in flight
// -- never 0, T4). 1 block/CU (>128 unified regs/wave caps at 8 waves/CU,
// all measured configs); setprio kept from r3.
__global__ __launch_bounds__(512, 2) void argmin_hi(
    const _Float16* __restrict__ Xh, const _Float16* __restrict__ Eh,
    const float* __restrict__ esq, float* __restrict__ bestf)
{
    __shared__ __align__(16) _Float16 sA[2][2][2][4096];   // [buf][kh][panel] 64KB

    const int tid  = threadIdx.x;
    const int bid  = blockIdx.x;
    const int bx   = bid & 31;           // E col-block: bx%8 fixed per XCD -> ~1MB L2 set
    const int by   = bid >> 5;           // X row-block
    const int lane = tid & 63, wave = tid >> 6;
    const int wm   = wave >> 2;          // 0..1: 128-row half
    const int wn   = wave & 3;           // 0..3: 64-col quarter
    const int colg = lane & 15, quad = lane >> 4;
    const int la8  = lane * 8;

    const _Float16* gA = Xh + (size_t)(2 * by) * 65536 + tid * 8;
    // per-wave B base in packed layout: panel (wn>>1), 64-col half (wn&1)
    const _Float16* gB = Eh + (size_t)(2 * bx + (wn >> 1)) * 65536
                            + (wn & 1) * 2048 + la8;

    auto stgA = [&](int t, int kh, int b) {
        const int c = (2 * t + kh) * 4096;
        gld16(gA + c,         &sA[b][kh][0][tid * 8]);
        gld16(gA + 65536 + c, &sA[b][kh][1][tid * 8]);
    };

    floatx4 acc[8][4];
    #pragma unroll
    for (int i = 0; i < 8; ++i)
        #pragma unroll
        for (int j = 0; j < 4; ++j) acc[i][j] = {0.f, 0.f, 0.f, 0.f};

    half8 bbA[4], bbB[4];

    // prologue: stage tile 0 (both kh) -> buf0 FIRST, then bb(0,kh0).
    // vmcnt(4) drains the 4 gld16 (oldest), leaves the 4 bb loads in flight.
    stgA(0, 0, 0); stgA(0, 1, 0);
    #pragma unroll
    for (int ni = 0; ni < 4; ++ni)
        bbA[ni] = *(const half8*)(gB + ni * 512);
    asm volatile("s_waitcnt vmcnt(4)" ::: "memory");
    __builtin_amdgcn_s_barrier();

    for (int t = 0; t < 8; ++t) {
        const int b = t & 1, nb = b ^ 1;
        const bool pf = (t < 7);
        const _Float16* A0 = &sA[b][0][wm][0];
        const _Float16* A1 = &sA[b][1][wm][0];
        half8 a[8];

        // ---- kh0: issue bb(t,kh1); a from LDS; 32 MFMA on bbA
        #pragma unroll
        for (int ni = 0; ni < 4; ++ni)
            bbB[ni] = *(const half8*)(gB + (2 * t + 1) * 4096 + ni * 512);
        #pragma unroll
        for (int j = 0; j < 8; ++j)
            a[j] = *(const half8*)&A0[(j >> 2) * 2048 + (j & 3) * 512 + la8];
        __builtin_amdgcn_s_setprio(1);
        #pragma unroll
        for (int j = 0; j < 8; ++j)
            #pragma unroll
            for (int ni = 0; ni < 4; ++ni)
                acc[j][ni] = __builtin_amdgcn_mfma_f32_16x16x32_f16(
                    a[j], bbA[ni], acc[j][ni], 0, 0, 0);
        __builtin_amdgcn_s_setprio(0);

        // ---- kh1: stage tile t+1 (both kh, gld16 FIRST), then bb(t+1,kh0);
        //      a from LDS; 32 MFMA on bbB
        if (pf) {
            stgA(t + 1, 0, nb); stgA(t + 1, 1, nb);
            #pragma unroll
            for (int ni = 0; ni < 4; ++ni)
                bbA[ni] = *(const half8*)(gB + (2 * t + 2) * 4096 + ni * 512);
        }
        #pragma unroll
        for (int j = 0; j < 8; ++j)
            a[j] = *(const half8*)&A1[(j >> 2) * 2048 + (j & 3) * 512 + la8];
        __builtin_amdgcn_s_setprio(1);
        #pragma unroll
        for (int j = 0; j < 8; ++j)
            #pragma unroll
            for (int ni = 0; ni < 4; ++ni)
                acc[j][ni] = __builtin_amdgcn_mfma_f32_16x16x32_f16(
                    a[j], bbB[ni], acc[j][ni], 0, 0, 0);
        __builtin_amdgcn_s_setprio(0);

        // ---- one sync per K-tile: publish tile t+1's A (drain the 4 gld16,
        //      keep the 4 bb loads in flight)
        if (pf) {
            asm volatile("s_waitcnt vmcnt(4)" ::: "memory");
            __builtin_amdgcn_s_barrier();
        }
    }

    // ---- epilogue: per-(mi,r) top-2 over the wave's 64 cols, then cross-wn
    // merge in LDS -> top-2 per 256-col block. sm lives in sA[0] (t=7 read
    // buf 1, disjoint); __syncthreads orders write vs merged read.
    float2* sm = (float2*)&sA[0][0][0][0];   // 8KB merge buffer
    const int n0 = bx * 256 + wn * 64;
    float eqv[4];
    #pragma unroll
    for (int ni = 0; ni < 4; ++ni) eqv[ni] = esq[n0 + ni * 16 + colg];
    const unsigned ob_base = ((unsigned)colg << 4) | ((unsigned)wn << 2);

    #pragma unroll
    for (int mi = 0; mi < 8; ++mi)
        #pragma unroll
        for (int r = 0; r < 4; ++r) {
            float w1 = INFINITY, w2 = INFINITY;
            #pragma unroll
            for (int ni = 0; ni < 4; ++ni) {
                const float dv = eqv[ni] - 2.0f * acc[mi][ni][r];
                const float key = __uint_as_float(
                    (__float_as_uint(dv) & 0xFFFFFF00u) | (ob_base | (unsigned)ni));
                w2 = fminf(w2, fmaxf(w1, key));
                w1 = fminf(w1, key);
            }
            #pragma unroll
            for (int off = 1; off < 16; off <<= 1) {
                const float p1 = __shfl_xor(w1, off);
                const float p2 = __shfl_xor(w2, off);
                w2 = fminf(fmaxf(w1, p1), fminf(w2, p2));
                w1 = fminf(w1, p1);
            }
            if (colg == 0) {
                const int row128 = mi * 16 + quad * 4 + r;
                float2 st; st.x = w1; st.y = w2;
                sm[(wm * 128 + row128) * 4 + wn] = st;
            }
        }
    __syncthreads();
    if (tid < 256) {
        float m1 = INFINITY, m2 = INFINITY;
        #pragma unroll
        for (int w = 0; w < 4; ++w) {
            const float2 p = sm[tid * 4 + w];
            m2 = fminf(fmaxf(m1, p.x), fminf(m2, p.y));
            m1 = fminf(m1, p.x);
        }
        float2 st; st.x = m1; st.y = m2;
        *(float2*)&bestf[(size_t)(by * 256 + tid) * 64 + bx * 2] = st;
    }
}

// ---------------- kernel: exact refine, ONE WAVE PER ROW ---------------------
// 64 lanes read the row's 64 stored keys (top-2 per 256-col block), wave-min
// -> threshold -> ballot survivors -> exact fp32 distance per survivor ->
// best index (u64 key: ties to lowest index) -> write index + residual.
__global__ __launch_bounds__(256) void refine_kernel(
    const float* __restrict__ X, const float* __restrict__ E,
    const float* __restrict__ bestf, float* __restrict__ out)
{
    const int lane = threadIdx.x & 63, wave = threadIdx.x >> 6;
    const int b = blockIdx.x * 4 + wave;

    const float val = bestf[(size_t)b * 64 + lane];
    // decode this slot's candidate column: slot = cb*2 + j, cb = 256-col block
    const unsigned bits = __float_as_uint(val);
    const int cb = lane >> 1;
    const int colg = (bits >> 4) & 15, wn = (bits >> 2) & 3, ni = bits & 3;
    const int col = cb * 256 + wn * 64 + ni * 16 + colg;

    float mn = val;
    #pragma unroll
    for (int off = 1; off < 64; off <<= 1) mn = fminf(mn, __shfl_xor(mn, off));

    const float4* xr = (const float4*)(X + (size_t)b * Dn);
    const float4 x0 = xr[lane * 2], x1 = xr[lane * 2 + 1];

    u64 bestk = ~0ull;
    u64 mask = __ballot(val <= mn + WINDOW);
    while (mask) {
        const int s = __builtin_ctzll(mask);
        mask &= mask - 1;
        const int c = __shfl(col, s);
        const float4* er = (const float4*)(E + (size_t)c * Dn);
        const float4 e0 = er[lane * 2], e1 = er[lane * 2 + 1];
        float p = e0.x*(e0.x - 2.f*x0.x) + e0.y*(e0.y - 2.f*x0.y)
                + e0.z*(e0.z - 2.f*x0.z) + e0.w*(e0.w - 2.f*x0.w)
                + e1.x*(e1.x - 2.f*x1.x) + e1.y*(e1.y - 2.f*x1.y)
                + e1.z*(e1.z - 2.f*x1.z) + e1.w*(e1.w - 2.f*x1.w);
        #pragma unroll
        for (int off = 1; off < 64; off <<= 1) p += __shfl_xor(p, off);
        const u64 k = ((u64)fkey(p) << 32) | (u64)(unsigned int)c;
        if (k < bestk) bestk = k;
    }

    const int idx = (int)(unsigned int)(bestk & 0xFFFFFFFFull);
    if (lane == 0) out[b] = (float)idx;
    const float4* er = (const float4*)(E + (size_t)idx * Dn);
    const float4 e0 = er[lane * 2], e1 = er[lane * 2 + 1];
    float4 r0, r1;
    r0.x = x0.x - e0.x; r0.y = x0.y - e0.y; r0.z = x0.z - e0.z; r0.w = x0.w - e0.w;
    r1.x = x1.x - e1.x; r1.y = x1.y - e1.y; r1.z = x1.z - e1.z; r1.w = x1.w - e1.w;
    float4* o = (float4*)(out + Bn + (size_t)b * Dn);
    o[lane * 2] = r0; o[lane * 2 + 1] = r1;
}

// ---------------- fallback (round-1 fp32 path, used only if ws too small) ----
#define KSPLIT 16
#define LDSW 132
__global__ __launch_bounds__(256, 2) void argmin_fp32(
    const float* __restrict__ X, const float* __restrict__ E,
    const float* __restrict__ esq, u64* __restrict__ best)
{
    __shared__ __align__(16) float Xs[16][LDSW];
    __shared__ __align__(16) float Es[16][LDSW];
    __shared__ u64 red[128][16];
    const int tid = threadIdx.x;
    const int tx = tid & 15, ty = tid >> 4;
    const int rowTile = blockIdx.x / KSPLIT;
    const int split   = blockIdx.x % KSPLIT;
    const int m0 = rowTile * 128;
    const int kbase = split * (Kn / KSPLIT);
    float bestv[8]; int besti[8];
    #pragma unroll
    for (int i = 0; i < 8; ++i) { bestv[i] = INFINITY; besti[i] = 0; }
    const int ldRow = tid >> 2, ldD = (tid & 3) * 4;
    for (int kt = 0; kt < (Kn / KSPLIT) / 128; ++kt) {
        const int k0 = kbase + kt * 128;
        float acc[8][8] = {};
        for (int dc = 0; dc < Dn / 16; ++dc) {
            const int d0 = dc * 16;
            float4 xa = *(const float4*)&X[(size_t)(m0 + ldRow)      * Dn + d0 + ldD];
            float4 xb = *(const float4*)&X[(size_t)(m0 + 64 + ldRow) * Dn + d0 + ldD];
            float4 ea = *(const float4*)&E[(size_t)(k0 + ldRow)      * Dn + d0 + ldD];
            float4 eb = *(const float4*)&E[(size_t)(k0 + 64 + ldRow) * Dn + d0 + ldD];
            __syncthreads();
            Xs[ldD+0][ldRow] = xa.x; Xs[ldD+1][ldRow] = xa.y;
            Xs[ldD+2][ldRow] = xa.z; Xs[ldD+3][ldRow] = xa.w;
            Xs[ldD+0][64+ldRow] = xb.x; Xs[ldD+1][64+ldRow] = xb.y;
            Xs[ldD+2][64+ldRow] = xb.z; Xs[ldD+3][64+ldRow] = xb.w;
            Es[ldD+0][ldRow] = ea.x; Es[ldD+1][ldRow] = ea.y;
            Es[ldD+2][ldRow] = ea.z; Es[ldD+3][ldRow] = ea.w;
            Es[ldD+0][64+ldRow] = eb.x; Es[ldD+1][64+ldRow] = eb.y;
            Es[ldD+2][64+ldRow] = eb.z; Es[ldD+3][64+ldRow] = eb.w;
            __syncthreads();
            #pragma unroll
            for (int d = 0; d < 16; ++d) {
                float a8[8], b8[8];
                *(float4*)&a8[0] = *(const float4*)&Xs[d][4*ty];
                *(float4*)&a8[4] = *(const float4*)&Xs[d][64 + 4*ty];
                *(float4*)&b8[0] = *(const float4*)&Es[d][4*tx];
                *(float4*)&b8[4] = *(const float4*)&Es[d][64 + 4*tx];
                #pragma unroll
                for (int i = 0; i < 8; ++i)
                    #pragma unroll
                    for (int j = 0; j < 8; ++j) acc[i][j] += a8[i] * b8[j];
            }
        }
        #pragma unroll
        for (int j = 0; j < 8; ++j) {
            const int c = k0 + ((j < 4) ? (4*tx + j) : (64 + 4*tx + (j - 4)));
            const float eq = esq[c];
            #pragma unroll
            for (int i = 0; i < 8; ++i) {
                float dval = eq - 2.0f * acc[i][j];
                if (dval < bestv[i]) { bestv[i] = dval; besti[i] = c; }
            }
        }
    }
    #pragma unroll
    for (int i = 0; i < 8; ++i) {
        int rloc = (i < 4) ? (4*ty + i) : (64 + 4*ty + (i - 4));
        red[rloc][tx] = ((u64)fkey(bestv[i]) << 32) | (u64)(unsigned int)besti[i];
    }
    __syncthreads();
    if (tid < 128) {
        u64 m = red[tid][0];
        #pragma unroll
        for (int t = 1; t < 16; ++t) { u64 v = red[tid][t]; if (v < m) m = v; }
        best[(size_t)(m0 + tid) * KSPLIT + split] = m;
    }
}

__global__ __launch_bounds__(256) void finalize_kernel(
    const float* __restrict__ X, const float* __restrict__ E,
    const u64* __restrict__ best, float* __restrict__ out, int nsplits)
{
    __shared__ int sidx[2];
    const int half = threadIdx.x >> 7;
    const int t    = threadIdx.x & 127;
    const int b    = blockIdx.x * 2 + half;
    if (t < 64) {
        u64 v = (t < nsplits) ? best[(size_t)b * nsplits + t] : ~0ull;
        #pragma unroll
        for (int off = 1; off < 64; off <<= 1) {
            u64 o = __shfl_xor(v, off);
            if (o < v) v = o;
        }
        if (t == 0) {
            int idx = (int)(unsigned int)(v & 0xFFFFFFFFull);
            sidx[half] = idx;
            out[b] = (float)idx;
        }
    }
    __syncthreads();
    const int idx = sidx[half];
    float4 x = ((const float4*)(X + (size_t)b * Dn))[t];
    float4 e = ((const float4*)(E + (size_t)idx * Dn))[t];
    float4 r; r.x = x.x - e.x; r.y = x.y - e.y; r.z = x.z - e.z; r.w = x.w - e.w;
    ((float4*)(out + Bn + (size_t)b * Dn))[t] = r;
}

extern "C" void kernel_launch(void* const* d_in, const int* in_sizes, int n_in,
                              void* d_out, int out_size, void* d_ws, size_t ws_size,
                              hipStream_t stream) {
    const float* X = (const float*)d_in[0];   // previous_residual [B, D]
    const float* E = (const float*)d_in[1];   // codebook_embeddings [K, D]
    float* out = (float*)d_out;               // [B] idx-as-float ++ [B*D] residual

    // fast-path ws: esq 32KB | Xh 8MB | Eh 8MB | bestf 2MB  (~18.3 MB)
    const size_t HB = (size_t)Bn * Dn * sizeof(_Float16);        // 8 MB
    const size_t BESTB = (size_t)Bn * 64 * sizeof(float);        // 2 MB
    const size_t NEED = 32768 + 2 * HB + BESTB;

    float* esq = (float*)d_ws;

    if (ws_size >= NEED) {
        _Float16* Xh = (_Float16*)((char*)d_ws + 32768);
        _Float16* Eh = (_Float16*)((char*)d_ws + 32768 + HB);
        float* bestf = (float*)((char*)d_ws + 32768 + 2 * HB);
        hipMemsetAsync((void*)esq, 0, Kn * sizeof(float), stream);
        convert_hi<<<2048, 256, 0, stream>>>(X, E, Xh, Eh, esq);
        argmin_hi<<<1024, 512, 0, stream>>>(Xh, Eh, esq, bestf);
        refine_kernel<<<Bn / 4, 256, 0, stream>>>(X, E, bestf, out);
    } else {
        u64* best = (u64*)((char*)d_ws + 32768);
        esq_kernel<<<Kn / 4, 256, 0, stream>>>(E, esq);
        argmin_fp32<<<(Bn / 128) * KSPLIT, 256, 0, stream>>>(X, E, esq, best);
        finalize_kernel<<<Bn / 2, 256, 0, stream>>>(X, E, best, out, KSPLIT);
    }
}

// Round 8
// 171.953 us; speedup vs baseline: 1.0900x; 1.0384x over previous
//
#include <hip/hip_runtime.h>

// Problem constants (fp32 RQ-VAE nearest-codebook step)
#define Bn 8192
#define Kn 8192
#define Dn 512
#define WINDOW 0.25f   // refine window: covers f16-noise + 8-bit mantissa packing

typedef _Float16 half8 __attribute__((ext_vector_type(8)));
typedef float floatx4 __attribute__((ext_vector_type(4)));
typedef unsigned long long u64;

// Order-preserving map float -> u32 (monotone under unsigned compare, finite inputs)
__device__ __forceinline__ unsigned int fkey(float f) {
    unsigned int u = __float_as_uint(f);
    return (u & 0x80000000u) ? ~u : (u | 0x80000000u);
}

// async global->LDS, 16B per lane (global_load_lds_dwordx4)
__device__ __forceinline__ void gld16(const _Float16* g, _Float16* l) {
    __builtin_amdgcn_global_load_lds(
        (const __attribute__((address_space(1))) unsigned int*)g,
        (__attribute__((address_space(3))) unsigned int*)l, 16, 0, 0);
}

// ---------------- kernel: e_sq (fallback path only) ----------------
__global__ __launch_bounds__(256) void esq_kernel(const float* __restrict__ E,
                                                  float* __restrict__ esq) {
    int wave = threadIdx.x >> 6;
    int lane = threadIdx.x & 63;
    int k = blockIdx.x * 4 + wave;
    const float4* row = (const float4*)(E + (size_t)k * Dn);
    float4 v0 = row[lane];
    float4 v1 = row[64 + lane];
    float s = v0.x*v0.x + v0.y*v0.y + v0.z*v0.z + v0.w*v0.w
            + v1.x*v1.x + v1.y*v1.y + v1.z*v1.z + v1.w*v1.w;
    #pragma unroll
    for (int off = 32; off > 0; off >>= 1) s += __shfl_down(s, off, 64);
    if (lane == 0) esq[k] = s;
}

// ---------------- kernel: fp32 -> f16 (hi), PACKED layout, + fused e_sq ------
// G[panel][chunk][slot]*8 halves, panel = 128 rows, chunk = 32 k-halves,
//   slot(row128, kq) = (row128>>6)*256 + ((row128>>4)&3)*64 + kq*16 + (row128&15)
// blocks [0,1024) pack X, [1024,2048) pack E (E blocks also atomicAdd e_sq
// partials; esq must be zeroed before launch).
__global__ __launch_bounds__(256) void convert_hi(
    const float* __restrict__ X, const float* __restrict__ E,
    _Float16* __restrict__ Xh, _Float16* __restrict__ Eh,
    float* __restrict__ esq)
{
    const bool isE = blockIdx.x >= 1024;
    const int pc = blockIdx.x & 1023;
    const int panel = pc >> 4;              // 64 panels of 128 rows
    const int chunk = pc & 15;              // 16 chunks of 32 halves
    const float* src = isE ? E : X;
    _Float16* dst = isE ? Eh : Xh;
    const int t = threadIdx.x;
    const int row = t >> 1;                 // [0,128)
    const int kh  = (t & 1) * 16;
    const float* p = &src[(size_t)(panel * 128 + row) * Dn + chunk * 32 + kh];
    float4 v[4];
    v[0] = *(const float4*)(p + 0);
    v[1] = *(const float4*)(p + 4);
    v[2] = *(const float4*)(p + 8);
    v[3] = *(const float4*)(p + 12);
    const int slotbase = ((row >> 6) << 8) + (((row >> 4) & 3) << 6) + (row & 15);
    #pragma unroll
    for (int j = 0; j < 2; ++j) {
        half8 h;
        #pragma unroll
        for (int q = 0; q < 2; ++q) {
            const float4 w = v[j * 2 + q];
            h[q*4+0]=(_Float16)w.x; h[q*4+1]=(_Float16)w.y;
            h[q*4+2]=(_Float16)w.z; h[q*4+3]=(_Float16)w.w;
        }
        const int kq = (t & 1) * 2 + j;
        const size_t off = ((size_t)(panel * 16 + chunk) * 512
                            + slotbase + kq * 16) * 8;
        *(half8*)&dst[off] = h;
    }
    if (isE) {
        float s = 0.f;
        #pragma unroll
        for (int i = 0; i < 4; ++i)
            s += v[i].x*v[i].x + v[i].y*v[i].y + v[i].z*v[i].z + v[i].w*v[i].w;
        s += __shfl_xor(s, 1);              // pair (kh=0, kh=16) -> 32-col partial
        if ((t & 1) == 0) atomicAdd(&esq[panel * 128 + row], s);
    }
}

// ---------------- kernel: hi-only MFMA, 128x256 tile, 4 waves/SIMD -----------
// d~(b,k) = e_sq[k] - 2*(xh.eh). DIAGNOSIS (r2-r6 invariant): Occupancy ~21%
// (2 waves/SIMD), MfmaUtil 24-30%, VALUBusy 23-29%, HBM <=11%, conflicts 0 in
// EVERY schedule -> latency-bound at minimum occupancy. Cause: 128x64 wave
// tile = 128 acc VGPRs -> >128 unified regs/wave -> HW caps 2 waves/SIMD
// (m69: occupancy halves at 64/128/256 regs). No schedule fixes that.
// FIX: wave tile 64x64 -> acc 4x4 floatx4 = 64 regs; __launch_bounds__(512,4)
// caps at 128 regs -> 4 waves/SIMD. Block = 128 rows x 256 cols, 8 waves
// (wm 2 x wn 4), BK=32 (one packed chunk), dbuf A(8KB)+B(16KB) x2 = 48KB ->
// 2 blocks/CU = 16 waves/CU. Schedule: stage(t+1) at top of iter t (targets
// the buffer whose reads completed before the prior barrier -> race-free),
// 16 MFMA, vmcnt(0)+barrier per tile; the drain is covered by the co-resident
// block's waves (m97 mechanism, finally available at 2 blocks/CU).
// Epilogue: LDS merge of 4 wn waves -> top-2 per 256-col block; bestf
// encoding IDENTICAL to r3 (refine unchanged).
__global__ __launch_bounds__(512, 4) void argmin_hi(
    const _Float16* __restrict__ Xh, const _Float16* __restrict__ Eh,
    const float* __restrict__ esq, float* __restrict__ bestf)
{
    __shared__ __align__(16) _Float16 sA[2][4096];      // [buf][128r x 32k] 16KB
    __shared__ __align__(16) _Float16 sB[2][2][4096];   // [buf][panel][...] 32KB

    const int tid  = threadIdx.x;
    const int bid  = blockIdx.x;
    const int bx   = bid & 31;           // 32 col-blocks of 256 (bx%8 -> XCD set)
    const int by   = bid >> 5;           // 64 row-blocks of 128
    const int lane = tid & 63, wave = tid >> 6;
    const int wm   = wave >> 2;          // 0..1: 64-row half
    const int wn   = wave & 3;           // 0..3: 64-col quarter
    const int colg = lane & 15, quad = lane >> 4;
    const int la8  = lane * 8;

    const _Float16* gA = Xh + (size_t)by * 65536 + tid * 8;
    const _Float16* gB = Eh + (size_t)(2 * bx) * 65536 + tid * 8;

    // stage chunk t into LDS buffer b (A: 1 gld16, B: 2 gld16 @ 512 thr)
    auto stage = [&](int t, int b) {
        gld16(gA + t * 4096,         &sA[b][tid * 8]);
        gld16(gB + t * 4096,         &sB[b][0][tid * 8]);
        gld16(gB + 65536 + t * 4096, &sB[b][1][tid * 8]);
    };

    floatx4 acc[4][4];
    #pragma unroll
    for (int i = 0; i < 4; ++i)
        #pragma unroll
        for (int j = 0; j < 4; ++j) acc[i][j] = {0.f, 0.f, 0.f, 0.f};

    // prologue: chunk 0 -> buf0, publish
    stage(0, 0);
    asm volatile("s_waitcnt vmcnt(0)" ::: "memory");
    __builtin_amdgcn_s_barrier();

    for (int t = 0; t < 16; ++t) {
        const int b = t & 1;
        // stage next chunk into the other buffer (its readers finished at the
        // end-of-(t-1) barrier)
        if (t < 15) stage(t + 1, b ^ 1);

        const _Float16* A0 = &sA[b][wm * 2048 + la8];
        const _Float16* B0 = &sB[b][wn >> 1][(wn & 1) * 2048 + la8];
        half8 a[4], bb[4];
        #pragma unroll
        for (int ni = 0; ni < 4; ++ni) bb[ni] = *(const half8*)&B0[ni * 512];
        #pragma unroll
        for (int mi = 0; mi < 4; ++mi) a[mi] = *(const half8*)&A0[mi * 512];

        __builtin_amdgcn_s_setprio(1);
        #pragma unroll
        for (int mi = 0; mi < 4; ++mi)
            #pragma unroll
            for (int ni = 0; ni < 4; ++ni)
                acc[mi][ni] = __builtin_amdgcn_mfma_f32_16x16x32_f16(
                    a[mi], bb[ni], acc[mi][ni], 0, 0, 0);
        __builtin_amdgcn_s_setprio(0);

        if (t < 15) {
            asm volatile("s_waitcnt vmcnt(0)" ::: "memory");
            __builtin_amdgcn_s_barrier();
        }
    }

    // ---- epilogue: per-(mi,r) top-2 over the wave's 64 cols, then cross-wn
    // merge in LDS -> top-2 per 256-col block (encoding identical to r3).
    // sm lives in sA[0] (4KB; t=15 read sA[1]/sB[1], disjoint).
    float2* sm = (float2*)&sA[0][0];
    const int n0 = bx * 256 + wn * 64;
    float eqv[4];
    #pragma unroll
    for (int ni = 0; ni < 4; ++ni) eqv[ni] = esq[n0 + ni * 16 + colg];
    const unsigned ob_base = ((unsigned)colg << 4) | ((unsigned)wn << 2);

    #pragma unroll
    for (int mi = 0; mi < 4; ++mi)
        #pragma unroll
        for (int r = 0; r < 4; ++r) {
            float w1 = INFINITY, w2 = INFINITY;
            #pragma unroll
            for (int ni = 0; ni < 4; ++ni) {
                const float dv = eqv[ni] - 2.0f * acc[mi][ni][r];
                const float key = __uint_as_float(
                    (__float_as_uint(dv) & 0xFFFFFF00u) | (ob_base | (unsigned)ni));
                w2 = fminf(w2, fmaxf(w1, key));
                w1 = fminf(w1, key);
            }
            #pragma unroll
            for (int off = 1; off < 16; off <<= 1) {
                const float p1 = __shfl_xor(w1, off);
                const float p2 = __shfl_xor(w2, off);
                w2 = fminf(fmaxf(w1, p1), fminf(w2, p2));
                w1 = fminf(w1, p1);
            }
            if (colg == 0) {
                const int row128 = wm * 64 + mi * 16 + quad * 4 + r;
                float2 st; st.x = w1; st.y = w2;
                sm[row128 * 4 + wn] = st;
            }
        }
    __syncthreads();
    if (tid < 128) {
        float m1 = INFINITY, m2 = INFINITY;
        #pragma unroll
        for (int w = 0; w < 4; ++w) {
            const float2 p = sm[tid * 4 + w];
            m2 = fminf(fmaxf(m1, p.x), fminf(m2, p.y));
            m1 = fminf(m1, p.x);
        }
        float2 st; st.x = m1; st.y = m2;
        *(float2*)&bestf[(size_t)(by * 128 + tid) * 64 + bx * 2] = st;
    }
}

// ---------------- kernel: exact refine, ONE WAVE PER ROW ---------------------
// 64 lanes read the row's 64 stored keys (top-2 per 256-col block), wave-min
// -> threshold -> ballot survivors -> exact fp32 distance per survivor ->
// best index (u64 key: ties to lowest index) -> write index + residual.
__global__ __launch_bounds__(256) void refine_kernel(
    const float* __restrict__ X, const float* __restrict__ E,
    const float* __restrict__ bestf, float* __restrict__ out)
{
    const int lane = threadIdx.x & 63, wave = threadIdx.x >> 6;
    const int b = blockIdx.x * 4 + wave;

    const float val = bestf[(size_t)b * 64 + lane];
    // decode this slot's candidate column: slot = cb*2 + j, cb = 256-col block
    const unsigned bits = __float_as_uint(val);
    const int cb = lane >> 1;
    const int colg = (bits >> 4) & 15, wn = (bits >> 2) & 3, ni = bits & 3;
    const int col = cb * 256 + wn * 64 + ni * 16 + colg;

    float mn = val;
    #pragma unroll
    for (int off = 1; off < 64; off <<= 1) mn = fminf(mn, __shfl_xor(mn, off));

    const float4* xr = (const float4*)(X + (size_t)b * Dn);
    const float4 x0 = xr[lane * 2], x1 = xr[lane * 2 + 1];

    u64 bestk = ~0ull;
    u64 mask = __ballot(val <= mn + WINDOW);
    while (mask) {
        const int s = __builtin_ctzll(mask);
        mask &= mask - 1;
        const int c = __shfl(col, s);
        const float4* er = (const float4*)(E + (size_t)c * Dn);
        const float4 e0 = er[lane * 2], e1 = er[lane * 2 + 1];
        float p = e0.x*(e0.x - 2.f*x0.x) + e0.y*(e0.y - 2.f*x0.y)
                + e0.z*(e0.z - 2.f*x0.z) + e0.w*(e0.w - 2.f*x0.w)
                + e1.x*(e1.x - 2.f*x1.x) + e1.y*(e1.y - 2.f*x1.y)
                + e1.z*(e1.z - 2.f*x1.z) + e1.w*(e1.w - 2.f*x1.w);
        #pragma unroll
        for (int off = 1; off < 64; off <<= 1) p += __shfl_xor(p, off);
        const u64 k = ((u64)fkey(p) << 32) | (u64)(unsigned int)c;
        if (k < bestk) bestk = k;
    }

    const int idx = (int)(unsigned int)(bestk & 0xFFFFFFFFull);
    if (lane == 0) out[b] = (float)idx;
    const float4* er = (const float4*)(E + (size_t)idx * Dn);
    const float4 e0 = er[lane * 2], e1 = er[lane * 2 + 1];
    float4 r0, r1;
    r0.x = x0.x - e0.x; r0.y = x0.y - e0.y; r0.z = x0.z - e0.z; r0.w = x0.w - e0.w;
    r1.x = x1.x - e1.x; r1.y = x1.y - e1.y; r1.z = x1.z - e1.z; r1.w = x1.w - e1.w;
    float4* o = (float4*)(out + Bn + (size_t)b * Dn);
    o[lane * 2] = r0; o[lane * 2 + 1] = r1;
}

// ---------------- fallback (round-1 fp32 path, used only if ws too small) ----
#define KSPLIT 16
#define LDSW 132
__global__ __launch_bounds__(256, 2) void argmin_fp32(
    const float* __restrict__ X, const float* __restrict__ E,
    const float* __restrict__ esq, u64* __restrict__ best)
{
    __shared__ __align__(16) float Xs[16][LDSW];
    __shared__ __align__(16) float Es[16][LDSW];
    __shared__ u64 red[128][16];
    const int tid = threadIdx.x;
    const int tx = tid & 15, ty = tid >> 4;
    const int rowTile = blockIdx.x / KSPLIT;
    const int split   = blockIdx.x % KSPLIT;
    const int m0 = rowTile * 128;
    const int kbase = split * (Kn / KSPLIT);
    float bestv[8]; int besti[8];
    #pragma unroll
    for (int i = 0; i < 8; ++i) { bestv[i] = INFINITY; besti[i] = 0; }
    const int ldRow = tid >> 2, ldD = (tid & 3) * 4;
    for (int kt = 0; kt < (Kn / KSPLIT) / 128; ++kt) {
        const int k0 = kbase + kt * 128;
        float acc[8][8] = {};
        for (int dc = 0; dc < Dn / 16; ++dc) {
            const int d0 = dc * 16;
            float4 xa = *(const float4*)&X[(size_t)(m0 + ldRow)      * Dn + d0 + ldD];
            float4 xb = *(const float4*)&X[(size_t)(m0 + 64 + ldRow) * Dn + d0 + ldD];
            float4 ea = *(const float4*)&E[(size_t)(k0 + ldRow)      * Dn + d0 + ldD];
            float4 eb = *(const float4*)&E[(size_t)(k0 + 64 + ldRow) * Dn + d0 + ldD];
            __syncthreads();
            Xs[ldD+0][ldRow] = xa.x; Xs[ldD+1][ldRow] = xa.y;
            Xs[ldD+2][ldRow] = xa.z; Xs[ldD+3][ldRow] = xa.w;
            Xs[ldD+0][64+ldRow] = xb.x; Xs[ldD+1][64+ldRow] = xb.y;
            Xs[ldD+2][64+ldRow] = xb.z; Xs[ldD+3][64+ldRow] = xb.w;
            Es[ldD+0][ldRow] = ea.x; Es[ldD+1][ldRow] = ea.y;
            Es[ldD+2][ldRow] = ea.z; Es[ldD+3][ldRow] = ea.w;
            Es[ldD+0][64+ldRow] = eb.x; Es[ldD+1][64+ldRow] = eb.y;
            Es[ldD+2][64+ldRow] = eb.z; Es[ldD+3][64+ldRow] = eb.w;
            __syncthreads();
            #pragma unroll
            for (int d = 0; d < 16; ++d) {
                float a8[8], b8[8];
                *(float4*)&a8[0] = *(const float4*)&Xs[d][4*ty];
                *(float4*)&a8[4] = *(const float4*)&Xs[d][64 + 4*ty];
                *(float4*)&b8[0] = *(const float4*)&Es[d][4*tx];
                *(float4*)&b8[4] = *(const float4*)&Es[d][64 + 4*tx];
                #pragma unroll
                for (int i = 0; i < 8; ++i)
                    #pragma unroll
                    for (int j = 0; j < 8; ++j) acc[i][j] += a8[i] * b8[j];
            }
        }
        #pragma unroll
        for (int j = 0; j < 8; ++j) {
            const int c = k0 + ((j < 4) ? (4*tx + j) : (64 + 4*tx + (j - 4)));
            const float eq = esq[c];
            #pragma unroll
            for (int i = 0; i < 8; ++i) {
                float dval = eq - 2.0f * acc[i][j];
                if (dval < bestv[i]) { bestv[i] = dval; besti[i] = c; }
            }
        }
    }
    #pragma unroll
    for (int i = 0; i < 8; ++i) {
        int rloc = (i < 4) ? (4*ty + i) : (64 + 4*ty + (i - 4));
        red[rloc][tx] = ((u64)fkey(bestv[i]) << 32) | (u64)(unsigned int)besti[i];
    }
    __syncthreads();
    if (tid < 128) {
        u64 m = red[tid][0];
        #pragma unroll
        for (int t = 1; t < 16; ++t) { u64 v = red[tid][t]; if (v < m) m = v; }
        best[(size_t)(m0 + tid) * KSPLIT + split] = m;
    }
}

__global__ __launch_bounds__(256) void finalize_kernel(
    const float* __restrict__ X, const float* __restrict__ E,
    const u64* __restrict__ best, float* __restrict__ out, int nsplits)
{
    __shared__ int sidx[2];
    const int half = threadIdx.x >> 7;
    const int t    = threadIdx.x & 127;
    const int b    = blockIdx.x * 2 + half;
    if (t < 64) {
        u64 v = (t < nsplits) ? best[(size_t)b * nsplits + t] : ~0ull;
        #pragma unroll
        for (int off = 1; off < 64; off <<= 1) {
            u64 o = __shfl_xor(v, off);
            if (o < v) v = o;
        }
        if (t == 0) {
            int idx = (int)(unsigned int)(v & 0xFFFFFFFFull);
            sidx[half] = idx;
            out[b] = (float)idx;
        }
    }
    __syncthreads();
    const int idx = sidx[half];
    float4 x = ((const float4*)(X + (size_t)b * Dn))[t];
    float4 e = ((const float4*)(E + (size_t)idx * Dn))[t];
    float4 r; r.x = x.x - e.x; r.y = x.y - e.y; r.z = x.z - e.z; r.w = x.w - e.w;
    ((float4*)(out + Bn + (size_t)b * Dn))[t] = r;
}

extern "C" void kernel_launch(void* const* d_in, const int* in_sizes, int n_in,
                              void* d_out, int out_size, void* d_ws, size_t ws_size,
                              hipStream_t stream) {
    const float* X = (const float*)d_in[0];   // previous_residual [B, D]
    const float* E = (const float*)d_in[1];   // codebook_embeddings [K, D]
    float* out = (float*)d_out;               // [B] idx-as-float ++ [B*D] residual

    // fast-path ws: esq 32KB | Xh 8MB | Eh 8MB | bestf 2MB  (~18.3 MB)
    const size_t HB = (size_t)Bn * Dn * sizeof(_Float16);        // 8 MB
    const size_t BESTB = (size_t)Bn * 64 * sizeof(float);        // 2 MB
    const size_t NEED = 32768 + 2 * HB + BESTB;

    float* esq = (float*)d_ws;

    if (ws_size >= NEED) {
        _Float16* Xh = (_Float16*)((char*)d_ws + 32768);
        _Float16* Eh = (_Float16*)((char*)d_ws + 32768 + HB);
        float* bestf = (float*)((char*)d_ws + 32768 + 2 * HB);
        hipMemsetAsync((void*)esq, 0, Kn * sizeof(float), stream);
        convert_hi<<<2048, 256, 0, stream>>>(X, E, Xh, Eh, esq);
        argmin_hi<<<2048, 512, 0, stream>>>(Xh, Eh, esq, bestf);
        refine_kernel<<<Bn / 4, 256, 0, stream>>>(X, E, bestf, out);
    } else {
        u64* best = (u64*)((char*)d_ws + 32768);
        esq_kernel<<<Kn / 4, 256, 0, stream>>>(E, esq);
        argmin_fp32<<<(Bn / 128) * KSPLIT, 256, 0, stream>>>(X, E, esq, best);
        finalize_kernel<<<Bn / 2, 256, 0, stream>>>(X, E, best, out, KSPLIT);
    }
}

// Round 10
// 170.043 us; speedup vs baseline: 1.1023x; 1.0112x over previous
//
#include <hip/hip_runtime.h>

// Problem constants (fp32 RQ-VAE nearest-codebook step)
#define Bn 8192
#define Kn 8192
#define Dn 512
#define WINDOW 0.25f   // refine window: covers f16-noise + 8-bit mantissa packing

typedef _Float16 half8 __attribute__((ext_vector_type(8)));
typedef float floatx4 __attribute__((ext_vector_type(4)));
typedef unsigned long long u64;

// Order-preserving map float -> u32 (monotone under unsigned compare, finite inputs)
__device__ __forceinline__ unsigned int fkey(float f) {
    unsigned int u = __float_as_uint(f);
    return (u & 0x80000000u) ? ~u : (u | 0x80000000u);
}

// async global->LDS, 16B per lane (global_load_lds_dwordx4)
__device__ __forceinline__ void gld16(const _Float16* g, _Float16* l) {
    __builtin_amdgcn_global_load_lds(
        (const __attribute__((address_space(1))) unsigned int*)g,
        (__attribute__((address_space(3))) unsigned int*)l, 16, 0, 0);
}

// ---------------- kernel: e_sq (fallback path only) ----------------
__global__ __launch_bounds__(256) void esq_kernel(const float* __restrict__ E,
                                                  float* __restrict__ esq) {
    int wave = threadIdx.x >> 6;
    int lane = threadIdx.x & 63;
    int k = blockIdx.x * 4 + wave;
    const float4* row = (const float4*)(E + (size_t)k * Dn);
    float4 v0 = row[lane];
    float4 v1 = row[64 + lane];
    float s = v0.x*v0.x + v0.y*v0.y + v0.z*v0.z + v0.w*v0.w
            + v1.x*v1.x + v1.y*v1.y + v1.z*v1.z + v1.w*v1.w;
    #pragma unroll
    for (int off = 32; off > 0; off >>= 1) s += __shfl_down(s, off, 64);
    if (lane == 0) esq[k] = s;
}

// ---------------- kernel: fp32 -> f16 (hi), PACKED layout, + fused e_sq ------
// G[panel][chunk][slot]*8 halves, panel = 128 rows, chunk = 32 k-halves,
//   slot(row128, kq) = (row128>>6)*256 + ((row128>>4)&3)*64 + kq*16 + (row128&15)
// blocks [0,1024) pack X, [1024,2048) pack E (E blocks also atomicAdd e_sq
// partials; esq must be zeroed before launch).
__global__ __launch_bounds__(256) void convert_hi(
    const float* __restrict__ X, const float* __restrict__ E,
    _Float16* __restrict__ Xh, _Float16* __restrict__ Eh,
    float* __restrict__ esq)
{
    const bool isE = blockIdx.x >= 1024;
    const int pc = blockIdx.x & 1023;
    const int panel = pc >> 4;              // 64 panels of 128 rows
    const int chunk = pc & 15;              // 16 chunks of 32 halves
    const float* src = isE ? E : X;
    _Float16* dst = isE ? Eh : Xh;
    const int t = threadIdx.x;
    const int row = t >> 1;                 // [0,128)
    const int kh  = (t & 1) * 16;
    const float* p = &src[(size_t)(panel * 128 + row) * Dn + chunk * 32 + kh];
    float4 v[4];
    v[0] = *(const float4*)(p + 0);
    v[1] = *(const float4*)(p + 4);
    v[2] = *(const float4*)(p + 8);
    v[3] = *(const float4*)(p + 12);
    const int slotbase = ((row >> 6) << 8) + (((row >> 4) & 3) << 6) + (row & 15);
    #pragma unroll
    for (int j = 0; j < 2; ++j) {
        half8 h;
        #pragma unroll
        for (int q = 0; q < 2; ++q) {
            const float4 w = v[j * 2 + q];
            h[q*4+0]=(_Float16)w.x; h[q*4+1]=(_Float16)w.y;
            h[q*4+2]=(_Float16)w.z; h[q*4+3]=(_Float16)w.w;
        }
        const int kq = (t & 1) * 2 + j;
        const size_t off = ((size_t)(panel * 16 + chunk) * 512
                            + slotbase + kq * 16) * 8;
        *(half8*)&dst[off] = h;
    }
    if (isE) {
        float s = 0.f;
        #pragma unroll
        for (int i = 0; i < 4; ++i)
            s += v[i].x*v[i].x + v[i].y*v[i].y + v[i].z*v[i].z + v[i].w*v[i].w;
        s += __shfl_xor(s, 1);              // pair (kh=0, kh=16) -> 32-col partial
        if ((t & 1) == 0) atomicAdd(&esq[panel * 128 + row], s);
    }
}

// ---------------- kernel: hi-only MFMA, 128x256, tri-buffer counted vmcnt ----
// d~(b,k) = e_sq[k] - 2*(xh.eh). Wave tile 64x64 (acc 4x4 = 64 VGPR), 8 waves
// (wm 2 x wn 4), __launch_bounds__(512,4) -> 128 unified regs -> 4 waves/SIMD
// (r8 VERIFIED: Occupancy 21->40%, 91us). Residual (r8): MfmaUtil 33% vs
// 36% = dur/33us-MFMA-floor -> per-interval vmcnt(0) drain with only ~1
// interval of issue slack; all 8 waves convoy (T4 lesson, m218: counted-vs-
// drain0 = +38-73%). FIX: THREE buffers (72KB <= 80KB -> still 2 blocks/CU),
// stage issued TWO intervals ahead, per-iter wait = counted vmcnt(3) (drain
// stage(t), leave stage(t+1)'s 3 loads in flight) - never 0 until the tail.
// Race-free by order: {vmcnt(3); barrier} FIRST (retires all readers of the
// buffer stage(t+2) will overwrite, = buf read in iter t-1), THEN stage(t+2),
// THEN reads+MFMA. #pragma unroll -> all buffer indices compile-time.
// Epilogue merge buffer in sA[1] (t=15 reads buf 0; disjoint). bestf encoding
// IDENTICAL to r3/r8 (refine unchanged).
__global__ __launch_bounds__(512, 4) void argmin_hi(
    const _Float16* __restrict__ Xh, const _Float16* __restrict__ Eh,
    const float* __restrict__ esq, float* __restrict__ bestf)
{
    __shared__ __align__(16) _Float16 sA[3][4096];      // [buf][128r x 32k] 24KB
    __shared__ __align__(16) _Float16 sB[3][2][4096];   // [buf][panel][...] 48KB

    const int tid  = threadIdx.x;
    const int bid  = blockIdx.x;
    const int bx   = bid & 31;           // 32 col-blocks of 256 (bx%8 -> XCD set)
    const int by   = bid >> 5;           // 64 row-blocks of 128
    const int lane = tid & 63, wave = tid >> 6;
    const int wm   = wave >> 2;          // 0..1: 64-row half
    const int wn   = wave & 3;           // 0..3: 64-col quarter
    const int colg = lane & 15, quad = lane >> 4;
    const int la8  = lane * 8;

    const _Float16* gA = Xh + (size_t)by * 65536 + tid * 8;
    const _Float16* gB = Eh + (size_t)(2 * bx) * 65536 + tid * 8;

    // stage chunk t into LDS buffer b (A: 1 gld16, B: 2 gld16 @ 512 thr)
    auto stage = [&](int t, int b) {
        gld16(gA + t * 4096,         &sA[b][tid * 8]);
        gld16(gB + t * 4096,         &sB[b][0][tid * 8]);
        gld16(gB + 65536 + t * 4096, &sB[b][1][tid * 8]);
    };

    floatx4 acc[4][4];
    #pragma unroll
    for (int i = 0; i < 4; ++i)
        #pragma unroll
        for (int j = 0; j < 4; ++j) acc[i][j] = {0.f, 0.f, 0.f, 0.f};

    // prologue: chunks 0,1 in flight (6 loads/thread)
    stage(0, 0);
    stage(1, 1);

    #pragma unroll
    for (int t = 0; t < 16; ++t) {
        const int b = t % 3;
        // publish chunk t: drain its 3 loads, keep chunk t+1's 3 in flight
        if (t < 15) asm volatile("s_waitcnt vmcnt(3)" ::: "memory");
        else        asm volatile("s_waitcnt vmcnt(0)" ::: "memory");
        __builtin_amdgcn_s_barrier();
        // stage chunk t+2 into buf (t+2)%3 = buffer read in iter t-1; the
        // barrier above retired all its readers -> race-free
        if (t + 2 < 16) stage(t + 2, (t + 2) % 3);

        const _Float16* A0 = &sA[b][wm * 2048 + la8];
        const _Float16* B0 = &sB[b][wn >> 1][(wn & 1) * 2048 + la8];
        half8 a[4], bb[4];
        #pragma unroll
        for (int ni = 0; ni < 4; ++ni) bb[ni] = *(const half8*)&B0[ni * 512];
        #pragma unroll
        for (int mi = 0; mi < 4; ++mi) a[mi] = *(const half8*)&A0[mi * 512];

        __builtin_amdgcn_s_setprio(1);
        #pragma unroll
        for (int mi = 0; mi < 4; ++mi)
            #pragma unroll
            for (int ni = 0; ni < 4; ++ni)
                acc[mi][ni] = __builtin_amdgcn_mfma_f32_16x16x32_f16(
                    a[mi], bb[ni], acc[mi][ni], 0, 0, 0);
        __builtin_amdgcn_s_setprio(0);
    }

    // ---- epilogue: per-(mi,r) top-2 over the wave's 64 cols, then cross-wn
    // merge in LDS -> top-2 per 256-col block (encoding identical to r3/r8).
    // sm lives in sA[1] (4KB): t=15 read buf 0; sA[1] last read at t=13 and
    // all waves passed the t=15 barrier since -> disjoint/retired.
    float2* sm = (float2*)&sA[1][0];
    const int n0 = bx * 256 + wn * 64;
    float eqv[4];
    #pragma unroll
    for (int ni = 0; ni < 4; ++ni) eqv[ni] = esq[n0 + ni * 16 + colg];
    const unsigned ob_base = ((unsigned)colg << 4) | ((unsigned)wn << 2);

    #pragma unroll
    for (int mi = 0; mi < 4; ++mi)
        #pragma unroll
        for (int r = 0; r < 4; ++r) {
            float w1 = INFINITY, w2 = INFINITY;
            #pragma unroll
            for (int ni = 0; ni < 4; ++ni) {
                const float dv = eqv[ni] - 2.0f * acc[mi][ni][r];
                const float key = __uint_as_float(
                    (__float_as_uint(dv) & 0xFFFFFF00u) | (ob_base | (unsigned)ni));
                w2 = fminf(w2, fmaxf(w1, key));
                w1 = fminf(w1, key);
            }
            #pragma unroll
            for (int off = 1; off < 16; off <<= 1) {
                const float p1 = __shfl_xor(w1, off);
                const float p2 = __shfl_xor(w2, off);
                w2 = fminf(fmaxf(w1, p1), fminf(w2, p2));
                w1 = fminf(w1, p1);
            }
            if (colg == 0) {
                const int row128 = wm * 64 + mi * 16 + quad * 4 + r;
                float2 st; st.x = w1; st.y = w2;
                sm[row128 * 4 + wn] = st;
            }
        }
    __syncthreads();
    if (tid < 128) {
        float m1 = INFINITY, m2 = INFINITY;
        #pragma unroll
        for (int w = 0; w < 4; ++w) {
            const float2 p = sm[tid * 4 + w];
            m2 = fminf(fmaxf(m1, p.x), fminf(m2, p.y));
            m1 = fminf(m1, p.x);
        }
        float2 st; st.x = m1; st.y = m2;
        *(float2*)&bestf[(size_t)(by * 128 + tid) * 64 + bx * 2] = st;
    }
}

// ---------------- kernel: exact refine, ONE WAVE PER ROW ---------------------
// 64 lanes read the row's 64 stored keys (top-2 per 256-col block), wave-min
// -> threshold -> ballot survivors -> exact fp32 distance per survivor ->
// best index (u64 key: ties to lowest index) -> write index + residual.
__global__ __launch_bounds__(256) void refine_kernel(
    const float* __restrict__ X, const float* __restrict__ E,
    const float* __restrict__ bestf, float* __restrict__ out)
{
    const int lane = threadIdx.x & 63, wave = threadIdx.x >> 6;
    const int b = blockIdx.x * 4 + wave;

    const float val = bestf[(size_t)b * 64 + lane];
    // decode this slot's candidate column: slot = cb*2 + j, cb = 256-col block
    const unsigned bits = __float_as_uint(val);
    const int cb = lane >> 1;
    const int colg = (bits >> 4) & 15, wn = (bits >> 2) & 3, ni = bits & 3;
    const int col = cb * 256 + wn * 64 + ni * 16 + colg;

    float mn = val;
    #pragma unroll
    for (int off = 1; off < 64; off <<= 1) mn = fminf(mn, __shfl_xor(mn, off));

    const float4* xr = (const float4*)(X + (size_t)b * Dn);
    const float4 x0 = xr[lane * 2], x1 = xr[lane * 2 + 1];

    u64 bestk = ~0ull;
    u64 mask = __ballot(val <= mn + WINDOW);
    while (mask) {
        const int s = __builtin_ctzll(mask);
        mask &= mask - 1;
        const int c = __shfl(col, s);
        const float4* er = (const float4*)(E + (size_t)c * Dn);
        const float4 e0 = er[lane * 2], e1 = er[lane * 2 + 1];
        float p = e0.x*(e0.x - 2.f*x0.x) + e0.y*(e0.y - 2.f*x0.y)
                + e0.z*(e0.z - 2.f*x0.z) + e0.w*(e0.w - 2.f*x0.w)
                + e1.x*(e1.x - 2.f*x1.x) + e1.y*(e1.y - 2.f*x1.y)
                + e1.z*(e1.z - 2.f*x1.z) + e1.w*(e1.w - 2.f*x1.w);
        #pragma unroll
        for (int off = 1; off < 64; off <<= 1) p += __shfl_xor(p, off);
        const u64 k = ((u64)fkey(p) << 32) | (u64)(unsigned int)c;
        if (k < bestk) bestk = k;
    }

    const int idx = (int)(unsigned int)(bestk & 0xFFFFFFFFull);
    if (lane == 0) out[b] = (float)idx;
    const float4* er = (const float4*)(E + (size_t)idx * Dn);
    const float4 e0 = er[lane * 2], e1 = er[lane * 2 + 1];
    float4 r0, r1;
    r0.x = x0.x - e0.x; r0.y = x0.y - e0.y; r0.z = x0.z - e0.z; r0.w = x0.w - e0.w;
    r1.x = x1.x - e1.x; r1.y = x1.y - e1.y; r1.z = x1.z - e1.z; r1.w = x1.w - e1.w;
    float4* o = (float4*)(out + Bn + (size_t)b * Dn);
    o[lane * 2] = r0; o[lane * 2 + 1] = r1;
}

// ---------------- fallback (round-1 fp32 path, used only if ws too small) ----
#define KSPLIT 16
#define LDSW 132
__global__ __launch_bounds__(256, 2) void argmin_fp32(
    const float* __restrict__ X, const float* __restrict__ E,
    const float* __restrict__ esq, u64* __restrict__ best)
{
    __shared__ __align__(16) float Xs[16][LDSW];
    __shared__ __align__(16) float Es[16][LDSW];
    __shared__ u64 red[128][16];
    const int tid = threadIdx.x;
    const int tx = tid & 15, ty = tid >> 4;
    const int rowTile = blockIdx.x / KSPLIT;
    const int split   = blockIdx.x % KSPLIT;
    const int m0 = rowTile * 128;
    const int kbase = split * (Kn / KSPLIT);
    float bestv[8]; int besti[8];
    #pragma unroll
    for (int i = 0; i < 8; ++i) { bestv[i] = INFINITY; besti[i] = 0; }
    const int ldRow = tid >> 2, ldD = (tid & 3) * 4;
    for (int kt = 0; kt < (Kn / KSPLIT) / 128; ++kt) {
        const int k0 = kbase + kt * 128;
        float acc[8][8] = {};
        for (int dc = 0; dc < Dn / 16; ++dc) {
            const int d0 = dc * 16;
            float4 xa = *(const float4*)&X[(size_t)(m0 + ldRow)      * Dn + d0 + ldD];
            float4 xb = *(const float4*)&X[(size_t)(m0 + 64 + ldRow) * Dn + d0 + ldD];
            float4 ea = *(const float4*)&E[(size_t)(k0 + ldRow)      * Dn + d0 + ldD];
            float4 eb = *(const float4*)&E[(size_t)(k0 + 64 + ldRow) * Dn + d0 + ldD];
            __syncthreads();
            Xs[ldD+0][ldRow] = xa.x; Xs[ldD+1][ldRow] = xa.y;
            Xs[ldD+2][ldRow] = xa.z; Xs[ldD+3][ldRow] = xa.w;
            Xs[ldD+0][64+ldRow] = xb.x; Xs[ldD+1][64+ldRow] = xb.y;
            Xs[ldD+2][64+ldRow] = xb.z; Xs[ldD+3][64+ldRow] = xb.w;
            Es[ldD+0][ldRow] = ea.x; Es[ldD+1][ldRow] = ea.y;
            Es[ldD+2][ldRow] = ea.z; Es[ldD+3][ldRow] = ea.w;
            Es[ldD+0][64+ldRow] = eb.x; Es[ldD+1][64+ldRow] = eb.y;
            Es[ldD+2][64+ldRow] = eb.z; Es[ldD+3][64+ldRow] = eb.w;
            __syncthreads();
            #pragma unroll
            for (int d = 0; d < 16; ++d) {
                float a8[8], b8[8];
                *(float4*)&a8[0] = *(const float4*)&Xs[d][4*ty];
                *(float4*)&a8[4] = *(const float4*)&Xs[d][64 + 4*ty];
                *(float4*)&b8[0] = *(const float4*)&Es[d][4*tx];
                *(float4*)&b8[4] = *(const float4*)&Es[d][64 + 4*tx];
                #pragma unroll
                for (int i = 0; i < 8; ++i)
                    #pragma unroll
                    for (int j = 0; j < 8; ++j) acc[i][j] += a8[i] * b8[j];
            }
        }
        #pragma unroll
        for (int j = 0; j < 8; ++j) {
            const int c = k0 + ((j < 4) ? (4*tx + j) : (64 + 4*tx + (j - 4)));
            const float eq = esq[c];
            #pragma unroll
            for (int i = 0; i < 8; ++i) {
                float dval = eq - 2.0f * acc[i][j];
                if (dval < bestv[i]) { bestv[i] = dval; besti[i] = c; }
            }
        }
    }
    #pragma unroll
    for (int i = 0; i < 8; ++i) {
        int rloc = (i < 4) ? (4*ty + i) : (64 + 4*ty + (i - 4));
        red[rloc][tx] = ((u64)fkey(bestv[i]) << 32) | (u64)(unsigned int)besti[i];
    }
    __syncthreads();
    if (tid < 128) {
        u64 m = red[tid][0];
        #pragma unroll
        for (int t = 1; t < 16; ++t) { u64 v = red[tid][t]; if (v < m) m = v; }
        best[(size_t)(m0 + tid) * KSPLIT + split] = m;
    }
}

__global__ __launch_bounds__(256) void finalize_kernel(
    const float* __restrict__ X, const float* __restrict__ E,
    const u64* __restrict__ best, float* __restrict__ out, int nsplits)
{
    __shared__ int sidx[2];
    const int half = threadIdx.x >> 7;
    const int t    = threadIdx.x & 127;
    const int b    = blockIdx.x * 2 + half;
    if (t < 64) {
        u64 v = (t < nsplits) ? best[(size_t)b * nsplits + t] : ~0ull;
        #pragma unroll
        for (int off = 1; off < 64; off <<= 1) {
            u64 o = __shfl_xor(v, off);
            if (o < v) v = o;
        }
        if (t == 0) {
            int idx = (int)(unsigned int)(v & 0xFFFFFFFFull);
            sidx[half] = idx;
            out[b] = (float)idx;
        }
    }
    __syncthreads();
    const int idx = sidx[half];
    float4 x = ((const float4*)(X + (size_t)b * Dn))[t];
    float4 e = ((const float4*)(E + (size_t)idx * Dn))[t];
    float4 r; r.x = x.x - e.x; r.y = x.y - e.y; r.z = x.z - e.z; r.w = x.w - e.w;
    ((float4*)(out + Bn + (size_t)b * Dn))[t] = r;
}

extern "C" void kernel_launch(void* const* d_in, const int* in_sizes, int n_in,
                              void* d_out, int out_size, void* d_ws, size_t ws_size,
                              hipStream_t stream) {
    const float* X = (const float*)d_in[0];   // previous_residual [B, D]
    const float* E = (const float*)d_in[1];   // codebook_embeddings [K, D]
    float* out = (float*)d_out;               // [B] idx-as-float ++ [B*D] residual

    // fast-path ws: esq 32KB | Xh 8MB | Eh 8MB | bestf 2MB  (~18.3 MB)
    const size_t HB = (size_t)Bn * Dn * sizeof(_Float16);        // 8 MB
    const size_t BESTB = (size_t)Bn * 64 * sizeof(float);        // 2 MB
    const size_t NEED = 32768 + 2 * HB + BESTB;

    float* esq = (float*)d_ws;

    if (ws_size >= NEED) {
        _Float16* Xh = (_Float16*)((char*)d_ws + 32768);
        _Float16* Eh = (_Float16*)((char*)d_ws + 32768 + HB);
        float* bestf = (float*)((char*)d_ws + 32768 + 2 * HB);
        hipMemsetAsync((void*)esq, 0, Kn * sizeof(float), stream);
        convert_hi<<<2048, 256, 0, stream>>>(X, E, Xh, Eh, esq);
        argmin_hi<<<2048, 512, 0, stream>>>(Xh, Eh, esq, bestf);
        refine_kernel<<<Bn / 4, 256, 0, stream>>>(X, E, bestf, out);
    } else {
        u64* best = (u64*)((char*)d_ws + 32768);
        esq_kernel<<<Kn / 4, 256, 0, stream>>>(E, esq);
        argmin_fp32<<<(Bn / 128) * KSPLIT, 256, 0, stream>>>(X, E, esq, best);
        finalize_kernel<<<Bn / 2, 256, 0, stream>>>(X, E, best, out, KSPLIT);
    }
}